// Round 8
// baseline (119.929 us; speedup 1.0000x reference)
//
#include <hip/hip_runtime.h>
#include <hip/hip_bf16.h>
#include <stdint.h>

typedef __bf16 bf16;
typedef __attribute__((ext_vector_type(8))) __bf16 bf16x8;
typedef __attribute__((ext_vector_type(4))) float f32x4;
typedef __attribute__((ext_vector_type(4))) unsigned int u32x4;

#define B_DIM 128
#define F_DIM 256
#define C_DIM 512
#define HID   2048
#define F2    128
#define C2    256
#define MROWS 16384

// ---- workspace: fragment-packed weights (1 MB each) ----
// w1pp frag fi = ((hc*4 + wn)*8 + t)*4 + n  -> 1024B frag [lane][8 bf16]
//   element: h = hc*256 + wn*64 + n*16 + (lane&15), k = t*32 + (lane>>4)*8 + e
// w2pp frag fi = ((wn*8 + hc)*8 + t)*4 + n
//   element: c2 = wn*64 + n*16 + (lane&15), kglob = hc*256 + t*32 + (lane>>4)*8 + e
static constexpr size_t OFF_W1P = 0;
static constexpr size_t OFF_W2  = (size_t)HID * C2 * 2;   // 1,048,576

__device__ __forceinline__ unsigned short bfbits(float f) {
    bf16 h = (bf16)f;
    return __builtin_bit_cast(unsigned short, h);
}

#define GLOADI(dst, a, imm) \
    asm volatile("global_load_dwordx4 %0, %1, off offset:%c2" : "=v"(dst) : "v"(a), "n"(imm))
#define WAITVM4() asm volatile("s_waitcnt vmcnt(4)" ::: "memory")
#define WAITVM0() asm volatile("s_waitcnt vmcnt(0)" ::: "memory")
#define SCHED0()  __builtin_amdgcn_sched_barrier(0)

__device__ __forceinline__ bf16x8 asbf(u32x4 v) { return __builtin_bit_cast(bf16x8, v); }

// ---------------- K0: prep — fold interp into W1, pack both weights ----------------
__global__ __launch_bounds__(256) void prep_kernel(
    const float* __restrict__ w1, const float* __restrict__ w2,
    bf16* __restrict__ w1pp, bf16* __restrict__ w2pp)
{
    const int blk = blockIdx.x;
    const int t = threadIdx.x;
    if (blk < 2048) {
        int idx = blk * 256 + t;
        int h = idx >> 8, k = idx & 255;
        const float* wrow = w1 + (size_t)h * C_DIM;
        float acc = 0.f;
        int jlo = (k == 0) ? 0 : (int)((float)(k - 1) * (511.0f / 255.0f));
        int jhi = (int)((float)(k + 1) * (511.0f / 255.0f)) + 1;
        if (jhi > 511) jhi = 511;
        for (int j = jlo; j <= jhi; ++j) {
            float pos = (float)j * (255.0f / 511.0f);
            int i0 = (int)pos;
            if (i0 > 254) i0 = 254;
            float w = pos - (float)i0;
            float coef = (i0 == k) ? (1.0f - w) : ((i0 + 1 == k) ? w : 0.0f);
            acc += coef * wrow[j];
        }
        size_t fi = ((((size_t)(h >> 8)) * 4 + ((h >> 6) & 3)) * 8 + (k >> 5)) * 4 + ((h >> 4) & 3);
        w1pp[fi * 512 + (size_t)((((k >> 3) & 3) << 4) | (h & 15)) * 8 + (k & 7)] = (bf16)acc;
    } else {
        int idx2 = (blk - 2048) * 256 + t;     // 0..524287
        int c2 = idx2 >> 11, h = idx2 & 2047;
        float v = w2[(size_t)c2 * HID + h];
        size_t fi = ((((size_t)(c2 >> 6)) * 8 + (h >> 8)) * 8 + ((h >> 5) & 7)) * 4 + ((c2 >> 4) & 3);
        w2pp[fi * 512 + (size_t)((((h >> 3) & 3) << 4) | (c2 & 15)) * 8 + (h & 7)] = (bf16)v;
    }
}

// ---------------- fused: DWT -> [GEMM1+GELU -> GEMM2]x8 -> iDWT ----------------
// 256 blocks x 1024 threads (16 waves = 4m x 4n). 64 rows/block.
// LDS 64KB: ll [64][256] bf16 row-major+XOR swz @0 ; Hs same @32768.
// Weight frags streamed from L2 via inline-asm global_load_dwordx4 with
// vmcnt(4) double-buffer; GEMM1-t7 chains GEMM2's first frags and vice versa.
__global__ __launch_bounds__(1024, 4) void fused_mlp(
    const bf16* __restrict__ w1pp, const bf16* __restrict__ w2pp,
    const float* __restrict__ b1, const float* __restrict__ b2,
    const float* __restrict__ x, float* __restrict__ out)
{
    __shared__ __align__(16) char smem[65536];

    const int tid = threadIdx.x;
    const int l   = tid & 63;
    const int wv  = tid >> 6;          // 0..15
    const int wm  = wv >> 2;           // 0..3: rows wm*16..+16
    const int wn  = wv & 3;            // 0..3: cols wn*64..+64
    const int lr  = l & 15;
    const int q   = l >> 4;            // 0..3
    const int lrx = (lr & 7) << 4;
    const int R0  = blockIdx.x * 64;

    const char* w1b = (const char*)w1pp;
    const char* w2b = (const char*)w2pp;

    u32x4 wreg[2][4];                  // weight frag double buffer (static-indexed)

    // ---- issue chunk-0 GEMM1 t=0 frags immediately (land under DWT fill) ----
    {
        const char* a0 = w1b + (size_t)(wn * 8) * 4096 + (size_t)l * 16;
        GLOADI(wreg[0][0], a0, 0);
        GLOADI(wreg[0][1], a0, 1024);
        GLOADI(wreg[0][2], a0, 2048);
        GLOADI(wreg[0][3], a0, 3072);
    }

    // ---- DWT fill: ll [64][256] bf16, row-major, byte ^= (row&7)<<4 ----
    {
        const int rr = tid >> 4;               // 0..63
        const int w0 = tid & 15;
        const int gbf = R0 + rr;
        const float* xr = x + ((size_t)(gbf >> 7) * F_DIM + (size_t)(gbf & 127) * 2) * C_DIM;
        const float* xs = xr + C_DIM;
#pragma unroll
        for (int half = 0; half < 2; ++half) {
            const int w = w0 + half * 16;      // 16B slot: cols w*8..+8
            float4 ra[4], rb[4];
#pragma unroll
            for (int i = 0; i < 4; ++i) {
                ra[i] = ((const float4*)xr)[w * 4 + i];
                rb[i] = ((const float4*)xs)[w * 4 + i];
            }
            const float* pa = (const float*)ra;
            const float* pb = (const float*)rb;
            bf16x8 pk;
#pragma unroll
            for (int e = 0; e < 8; ++e)
                pk[e] = (bf16)(0.5f * (pa[2*e] + pa[2*e+1] + pb[2*e] + pb[2*e+1]));
            int by = rr * 512 + ((w * 16) ^ ((rr & 7) << 4));
            *(bf16x8*)(smem + by) = pk;
        }
    }
    __syncthreads();

    f32x4 acc2[4];
#pragma unroll
    for (int n = 0; n < 4; ++n) acc2[n] = (f32x4){0.f, 0.f, 0.f, 0.f};

    const int arow = (wm * 16 + lr) * 512;     // ll row byte base
    const int hrow = 32768 + arow;             // Hs row byte base

#pragma unroll 1
    for (int hc = 0; hc < 8; ++hc) {
        const char* a2 = w2b + (size_t)((wn * 8 + hc) * 8) * 4096 + (size_t)l * 16;

        // ---- GEMM1 over K=256: wave = 16 rows x 64 cols ----
        f32x4 acc1[4];
#pragma unroll
        for (int n = 0; n < 4; ++n) acc1[n] = (f32x4){0.f, 0.f, 0.f, 0.f};

        bf16x8 afc = *(const bf16x8*)(smem + arow + ((q * 16) ^ lrx));
        {
            const char* a1t = w1b + (size_t)((hc * 4 + wn) * 8) * 4096 + (size_t)l * 16 + 4096;
#pragma unroll
            for (int t = 0; t < 8; ++t) {
                if (t < 7) {
                    GLOADI(wreg[(t + 1) & 1][0], a1t, 0);
                    GLOADI(wreg[(t + 1) & 1][1], a1t, 1024);
                    GLOADI(wreg[(t + 1) & 1][2], a1t, 2048);
                    GLOADI(wreg[(t + 1) & 1][3], a1t, 3072);
                    a1t += 4096;
                } else {               // chain: GEMM2 t=0 frags (land under GELU)
                    GLOADI(wreg[0][0], a2, 0);
                    GLOADI(wreg[0][1], a2, 1024);
                    GLOADI(wreg[0][2], a2, 2048);
                    GLOADI(wreg[0][3], a2, 3072);
                }
                bf16x8 afn;
                if (t < 7)
                    afn = *(const bf16x8*)(smem + arow + (((t + 1) * 64 + q * 16) ^ lrx));
                WAITVM4();
                SCHED0();
#pragma unroll
                for (int n = 0; n < 4; ++n)
                    acc1[n] = __builtin_amdgcn_mfma_f32_16x16x32_bf16(afc, asbf(wreg[t & 1][n]), acc1[n], 0, 0, 0);
                if (t < 7) afc = afn;
            }
        }

        // ---- GELU -> Hs (b32 pair-writes via DPP lane^1 swap) ----
#pragma unroll
        for (int n = 0; n < 4; ++n) {
            const float bs = b1[hc * 256 + wn * 64 + n * 16 + lr];
#pragma unroll
            for (int j = 0; j < 4; ++j) {
                float v = acc1[n][j] + bs;
                float tt = v * (0.79788456080f + 0.03567740814f * v * v);
                float g = v / (1.0f + __expf(-2.0f * tt));
                float gp = __builtin_bit_cast(float,
                    __builtin_amdgcn_mov_dpp(__builtin_bit_cast(int, g), 0xB1, 0xF, 0xF, true));
                if (!(l & 1)) {
                    unsigned u = (unsigned)bfbits(g) | ((unsigned)bfbits(gp) << 16);
                    int row = wm * 16 + q * 4 + j;
                    int col = wn * 64 + n * 16 + lr;          // even
                    int by = 32768 + row * 512 + ((col * 2) ^ ((row & 7) << 4));
                    *(unsigned*)(smem + by) = u;
                }
            }
        }
        __syncthreads();   // Hs ready (drains chained GEMM2 t0 frags too)

        // ---- GEMM2 over K=256 (this chunk): wave = 16 rows x 64 c2 ----
        bf16x8 hfc = *(const bf16x8*)(smem + hrow + ((q * 16) ^ lrx));
        {
            const char* a2t = a2 + 4096;
#pragma unroll
            for (int t = 0; t < 8; ++t) {
                if (t < 7) {
                    GLOADI(wreg[(t + 1) & 1][0], a2t, 0);
                    GLOADI(wreg[(t + 1) & 1][1], a2t, 1024);
                    GLOADI(wreg[(t + 1) & 1][2], a2t, 2048);
                    GLOADI(wreg[(t + 1) & 1][3], a2t, 3072);
                    a2t += 4096;
                }
                bf16x8 hfn;
                if (t < 7)
                    hfn = *(const bf16x8*)(smem + hrow + (((t + 1) * 64 + q * 16) ^ lrx));
                if (t < 7) {
                    WAITVM4();
                } else if (hc < 7) {   // chain: next chunk GEMM1 t=0 frags
                    const char* a1x = w1b + (size_t)(((hc + 1) * 4 + wn) * 8) * 4096 + (size_t)l * 16;
                    GLOADI(wreg[0][0], a1x, 0);
                    GLOADI(wreg[0][1], a1x, 1024);
                    GLOADI(wreg[0][2], a1x, 2048);
                    GLOADI(wreg[0][3], a1x, 3072);
                    WAITVM4();
                } else {
                    WAITVM0();
                }
                SCHED0();
#pragma unroll
                for (int n = 0; n < 4; ++n)
                    acc2[n] = __builtin_amdgcn_mfma_f32_16x16x32_bf16(hfc, asbf(wreg[t & 1][n]), acc2[n], 0, 0, 0);
                if (t < 7) hfc = hfn;
            }
        }
        __syncthreads();   // Hs consumed before next chunk's GELU overwrites
    }

    // ---- epilogue: out = x + 0.5*(ll_new - ll_old), broadcast over 2x2 ----
#pragma unroll
    for (int n = 0; n < 4; ++n) {
        const int c2 = wn * 64 + n * 16 + lr;
        const float bs = b2[c2];
#pragma unroll
        for (int j = 0; j < 4; ++j) {
            const int gbf = R0 + wm * 16 + q * 4 + j;
            const int b = gbf >> 7, f2 = gbf & 127;
            const float* xr = x + ((size_t)b * F_DIM + (size_t)f2 * 2) * C_DIM;
            float2 p0 = ((const float2*)xr)[c2];
            float2 p1 = ((const float2*)(xr + C_DIM))[c2];
            float llo = 0.5f * (p0.x + p0.y + p1.x + p1.y);
            float d = 0.5f * ((acc2[n][j] + bs) - llo);
            float2 o0, o1;
            o0.x = p0.x + d; o0.y = p0.y + d;
            o1.x = p1.x + d; o1.y = p1.y + d;
            float* orow = out + ((size_t)b * F_DIM + (size_t)f2 * 2) * C_DIM;
            ((float2*)orow)[c2] = o0;
            ((float2*)(orow + C_DIM))[c2] = o1;
        }
    }
}

extern "C" void kernel_launch(void* const* d_in, const int* in_sizes, int n_in,
                              void* d_out, int out_size, void* d_ws, size_t ws_size,
                              hipStream_t stream) {
    const float* x     = (const float*)d_in[0];
    const float* fc1_w = (const float*)d_in[1];
    const float* fc1_b = (const float*)d_in[2];
    const float* fc2_w = (const float*)d_in[3];
    const float* fc2_b = (const float*)d_in[4];
    float* out = (float*)d_out;

    char* ws = (char*)d_ws;
    bf16* w1pp = (bf16*)(ws + OFF_W1P);
    bf16* w2pp = (bf16*)(ws + OFF_W2);

    prep_kernel<<<4096, 256, 0, stream>>>(fc1_w, fc2_w, w1pp, w2pp);
    fused_mlp<<<MROWS / 64, 1024, 0, stream>>>(w1pp, w2pp, fc1_b, fc2_b, x, out);
}

// Round 11
// 108.781 us; speedup vs baseline: 1.1025x; 1.1025x over previous
//
#include <hip/hip_runtime.h>
#include <hip/hip_bf16.h>
#include <stdint.h>

typedef __bf16 bf16;
typedef __attribute__((ext_vector_type(8)))  __bf16 bf16x8;
typedef __attribute__((ext_vector_type(16))) float  f32x16;

#define B_DIM 128
#define F_DIM 256
#define C_DIM 512
#define HID   2048
#define C2    256
#define MROWS 16384

// ws: w1pp 1MB | w2pp 1MB   (fragment-packed B-operands for 32x32x16 MFMA)
// B-frag pack (both weights): element W[n][k] lives at
//   frag = (n>>5)*NKF + (k>>4),  lane = ((k>>3)&1)<<5 | (n&31),  e = k&7
//   byte = frag*1024 + lane*16 + e*2        (NKF: W1'=16, W2=128)
static constexpr size_t OFF_W1 = 0;
static constexpr size_t OFF_W2 = 1u << 20;

__device__ __forceinline__ unsigned short bfbits(float f) {
    bf16 h = (bf16)f;
    return __builtin_bit_cast(unsigned short, h);
}

// ---------------- prep: fold interp into W1 + pack both weights as B-frags ----
__global__ __launch_bounds__(256) void prep_kernel(
    const float* __restrict__ w1, const float* __restrict__ w2,
    bf16* __restrict__ w1pp, bf16* __restrict__ w2pp)
{
    const int blk = blockIdx.x;
    const int t = threadIdx.x;
    if (blk < 2048) {
        int idx = blk * 256 + t;
        int h = idx >> 8, k = idx & 255;
        const float* wrow = w1 + (size_t)h * C_DIM;
        float acc = 0.f;
        int jlo = (k == 0) ? 0 : (int)((float)(k - 1) * (511.0f / 255.0f));
        int jhi = (int)((float)(k + 1) * (511.0f / 255.0f)) + 1;
        if (jhi > 511) jhi = 511;
        for (int j = jlo; j <= jhi; ++j) {
            float pos = (float)j * (255.0f / 511.0f);
            int i0 = (int)pos;
            if (i0 > 254) i0 = 254;
            float w = pos - (float)i0;
            float coef = (i0 == k) ? (1.0f - w) : ((i0 + 1 == k) ? w : 0.0f);
            acc += coef * wrow[j];
        }
        size_t frag = (size_t)(h >> 5) * 16 + (k >> 4);
        size_t lane = (size_t)(((k >> 3) & 1) << 5 | (h & 31));
        w1pp[frag * 512 + lane * 8 + (k & 7)] = (bf16)acc;
    } else {
        int idx2 = (blk - 2048) * 256 + t;     // 0..524287
        int c2 = idx2 >> 11, hid = idx2 & 2047;
        float v = w2[(size_t)c2 * HID + hid];
        size_t frag = (size_t)(c2 >> 5) * 128 + (hid >> 4);
        size_t lane = (size_t)(((hid >> 3) & 1) << 5 | (c2 & 31));
        w2pp[frag * 512 + lane * 8 + (hid & 7)] = (bf16)v;
    }
}

// ---------------- fused: DWT -> [G1 -> GELU/2 -> G2/2]x4 chunks -> iDWT -------
// 256 blocks x 512 thr (8 waves). Block = 64 rows, full 2048 hid (4 chunks x 512).
// LDS 64KB static: ll A-frag-packed 32KB @0 ; Hs half-chunk (256 hid) 32KB @32768.
// A-frag pack: slot=((kf*2+rg)*64+lane)*16 ; lane=((k>>3)&1)<<5|(row&31) ; e=k&7.
// All weight B-frags are plain C++ 16B/lane loads from L2 (depth-4 register ring,
// compiler-scheduled waits -> no asm-load hazard).
__global__ __launch_bounds__(512, 2) void fused_mlp(
    const bf16* __restrict__ w1pp, const bf16* __restrict__ w2pp,
    const float* __restrict__ b1, const float* __restrict__ b2,
    const float* __restrict__ x, float* __restrict__ out)
{
    __shared__ __align__(16) char smem[65536];
    char* hsm = smem + 32768;

    const int tid = threadIdx.x;
    const int l   = tid & 63;
    const int wv  = tid >> 6;          // 0..7
    const int R0  = blockIdx.x * 64;
    const char* w1B = (const char*)w1pp;
    const char* w2B = (const char*)w2pp;

    // ---- DWT fill: ll A-frag-packed (element check: (r=5,c2=37) -> byte
    //      ((2*2+0)*64+5)*16+10, matches reader lane 5, ks 2, e 5) ----
    {
        const int r  = tid >> 3;               // 0..63
        const int rg = r >> 5;
        const int gbf = R0 + r;
        const float* xr0 = x + ((size_t)(gbf >> 7) * F_DIM + (size_t)(gbf & 127) * 2) * C_DIM;
        const float* xr1 = xr0 + C_DIM;
#pragma unroll
        for (int jj = 0; jj < 4; ++jj) {
            int j = (tid & 7) * 4 + jj;        // c2-group of 8: c2 = 8j..8j+7
            float4 a[4], b[4];
#pragma unroll
            for (int i = 0; i < 4; ++i) {
                a[i] = ((const float4*)xr0)[j * 4 + i];
                b[i] = ((const float4*)xr1)[j * 4 + i];
            }
            const float* pa = (const float*)a;
            const float* pb = (const float*)b;
            bf16x8 pk;
#pragma unroll
            for (int e = 0; e < 8; ++e)
                pk[e] = (bf16)(0.5f * (pa[2*e] + pa[2*e+1] + pb[2*e] + pb[2*e+1]));
            int kf   = j >> 1;
            int lane = ((j & 1) << 5) | (r & 31);
            *(bf16x8*)(smem + (((kf * 2 + rg) * 64) + lane) * 16) = pk;
        }
    }
    __syncthreads();

    f32x16 acc2_0{}, acc2_1{};                 // [rg] : 64 rows x 32 c2 per wave

    // GELU(+bias) -> Hs half-buffer (pair-packed b32 via DPP lane^1 swap)
    auto geluwrite = [&](const f32x16& A, int nf, int rg, int hc) {
        const float bs = b1[hc * 512 + wv * 64 + nf * 32 + (l & 31)];
#pragma unroll
        for (int reg = 0; reg < 16; ++reg) {
            float v = A[reg] + bs;
            float tt = v * (0.79788456080f + 0.03567740814f * v * v);
            float g = v / (1.0f + __expf(-2.0f * tt));
            float gp = __builtin_bit_cast(float,
                __builtin_amdgcn_mov_dpp(__builtin_bit_cast(int, g), 0xB1, 0xF, 0xF, true));
            if (!(l & 1)) {
                unsigned u = (unsigned)bfbits(g) | ((unsigned)bfbits(gp) << 16);
                int crow  = (reg & 3) + 8 * (reg >> 2) + 4 * (l >> 5);
                int kf2   = (wv & 3) * 4 + nf * 2 + ((l & 31) >> 4);
                int lane2 = ((l >> 3) & 1) << 5 | crow;
                *(unsigned*)(hsm + ((kf2 * 2 + rg) * 64 + lane2) * 16 + (l & 7) * 2) = u;
            }
        }
    };

    // GEMM2 over one 256-hid half (16 ksteps), acc2 += Hs x W2
    auto g2half = [&](int hc, int hs) {
        bf16x8 wr2[4];
        const char* w2f = w2B + ((size_t)(wv * 128 + hc * 32 + hs * 16)) * 1024 + (size_t)l * 16;
#pragma unroll
        for (int i = 0; i < 4; ++i) wr2[i] = *(const bf16x8*)(w2f + i * 1024);
#pragma unroll
        for (int ks = 0; ks < 16; ++ks) {
            bf16x8 h0 = *(const bf16x8*)(hsm + ((ks * 2 + 0) * 64 + l) * 16);
            bf16x8 h1 = *(const bf16x8*)(hsm + ((ks * 2 + 1) * 64 + l) * 16);
            acc2_0 = __builtin_amdgcn_mfma_f32_32x32x16_bf16(h0, wr2[ks & 3], acc2_0, 0, 0, 0);
            acc2_1 = __builtin_amdgcn_mfma_f32_32x32x16_bf16(h1, wr2[ks & 3], acc2_1, 0, 0, 0);
            if (ks + 4 < 16)
                wr2[ks & 3] = *(const bf16x8*)(w2f + (ks + 4) * 1024);
        }
    };

#pragma unroll 1
    for (int hc = 0; hc < 4; ++hc) {
        // ---- GEMM1: acc1[nf][rg] = ll x W1'chunk, wave = 64 rows x 64 hid ----
        f32x16 a1_00{}, a1_01{}, a1_10{}, a1_11{};
        bf16x8 wr0[4], wr1[4];
        const char* w1f0 = w1B + ((size_t)((hc * 16 + wv * 2 + 0) * 16)) * 1024 + (size_t)l * 16;
        const char* w1f1 = w1B + ((size_t)((hc * 16 + wv * 2 + 1) * 16)) * 1024 + (size_t)l * 16;
#pragma unroll
        for (int i = 0; i < 4; ++i) {
            wr0[i] = *(const bf16x8*)(w1f0 + i * 1024);
            wr1[i] = *(const bf16x8*)(w1f1 + i * 1024);
        }
#pragma unroll
        for (int ks = 0; ks < 16; ++ks) {
            bf16x8 a0 = *(const bf16x8*)(smem + ((ks * 2 + 0) * 64 + l) * 16);
            bf16x8 a1 = *(const bf16x8*)(smem + ((ks * 2 + 1) * 64 + l) * 16);
            a1_00 = __builtin_amdgcn_mfma_f32_32x32x16_bf16(a0, wr0[ks & 3], a1_00, 0, 0, 0);
            a1_01 = __builtin_amdgcn_mfma_f32_32x32x16_bf16(a1, wr0[ks & 3], a1_01, 0, 0, 0);
            a1_10 = __builtin_amdgcn_mfma_f32_32x32x16_bf16(a0, wr1[ks & 3], a1_10, 0, 0, 0);
            a1_11 = __builtin_amdgcn_mfma_f32_32x32x16_bf16(a1, wr1[ks & 3], a1_11, 0, 0, 0);
            if (ks + 4 < 16) {
                wr0[ks & 3] = *(const bf16x8*)(w1f0 + (ks + 4) * 1024);
                wr1[ks & 3] = *(const bf16x8*)(w1f1 + (ks + 4) * 1024);
            }
        }

        // ---- half A (hid 0..255 of chunk): waves 0-3 own those columns ----
        if (wv < 4) {
            geluwrite(a1_00, 0, 0, hc); geluwrite(a1_01, 0, 1, hc);
            geluwrite(a1_10, 1, 0, hc); geluwrite(a1_11, 1, 1, hc);
        }
        __syncthreads();
        g2half(hc, 0);
        __syncthreads();
        // ---- half B (hid 256..511 of chunk): waves 4-7 ----
        if (wv >= 4) {
            geluwrite(a1_00, 0, 0, hc); geluwrite(a1_01, 0, 1, hc);
            geluwrite(a1_10, 1, 0, hc); geluwrite(a1_11, 1, 1, hc);
        }
        __syncthreads();
        g2half(hc, 1);
        __syncthreads();
    }

    // ---- epilogue: bias + iDWT (out = x + 0.5*(ll_new - ll_old)) ----
    {
        const int c2 = wv * 32 + (l & 31);
        const float bs = b2[c2];
#pragma unroll
        for (int rg = 0; rg < 2; ++rg) {
            const f32x16& A = rg ? acc2_1 : acc2_0;
#pragma unroll
            for (int reg = 0; reg < 16; ++reg) {
                int R = R0 + rg * 32 + (reg & 3) + 8 * (reg >> 2) + 4 * (l >> 5);
                int b = R >> 7, f2 = R & 127;
                const float* xr = x + ((size_t)b * F_DIM + (size_t)f2 * 2) * C_DIM;
                float2 p0 = ((const float2*)xr)[c2];
                float2 p1 = ((const float2*)(xr + C_DIM))[c2];
                float llo = 0.5f * (p0.x + p0.y + p1.x + p1.y);
                float d = 0.5f * ((A[reg] + bs) - llo);
                float2 o0, o1;
                o0.x = p0.x + d; o0.y = p0.y + d;
                o1.x = p1.x + d; o1.y = p1.y + d;
                float* orow = out + ((size_t)b * F_DIM + (size_t)f2 * 2) * C_DIM;
                ((float2*)orow)[c2] = o0;
                ((float2*)(orow + C_DIM))[c2] = o1;
            }
        }
    }
}

extern "C" void kernel_launch(void* const* d_in, const int* in_sizes, int n_in,
                              void* d_out, int out_size, void* d_ws, size_t ws_size,
                              hipStream_t stream) {
    const float* x     = (const float*)d_in[0];
    const float* fc1_w = (const float*)d_in[1];
    const float* fc1_b = (const float*)d_in[2];
    const float* fc2_w = (const float*)d_in[3];
    const float* fc2_b = (const float*)d_in[4];
    float* out = (float*)d_out;

    char* ws = (char*)d_ws;
    bf16* w1pp = (bf16*)(ws + OFF_W1);
    bf16* w2pp = (bf16*)(ws + OFF_W2);

    prep_kernel<<<4096, 256, 0, stream>>>(fc1_w, fc2_w, w1pp, w2pp);
    fused_mlp<<<MROWS / 64, 512, 0, stream>>>(w1pp, w2pp, fc1_b, fc2_b, x, out);
}

// Round 12
// 100.769 us; speedup vs baseline: 1.1901x; 1.0795x over previous
//
#include <hip/hip_runtime.h>
#include <hip/hip_bf16.h>
#include <stdint.h>

typedef __bf16 bf16;
typedef __attribute__((ext_vector_type(8)))  __bf16 bf16x8;
typedef __attribute__((ext_vector_type(16))) float  f32x16;

#define B_DIM 128
#define F_DIM 256
#define C_DIM 512
#define HID   2048
#define C2    256
#define MROWS 16384

// ws: w1pp 1MB | w2pp 1MB   (B-fragment-packed weights for 32x32x16 MFMA)
// pack: element W[n][k] -> frag=(n>>5)*NKF+(k>>4), lane=((k>>3)&1)<<5|(n&31), e=k&7
//       byte = frag*1024 + lane*16 + e*2     (NKF: W1'=16, W2=128)
static constexpr size_t OFF_W1 = 0;
static constexpr size_t OFF_W2 = 1u << 20;

__device__ __forceinline__ unsigned short bfbits(float f) {
    bf16 h = (bf16)f;
    return __builtin_bit_cast(unsigned short, h);
}
#define SCHED0() __builtin_amdgcn_sched_barrier(0)

// ---------------- prep: fold interp into W1 + pack both weights as B-frags ----
__global__ __launch_bounds__(256) void prep_kernel(
    const float* __restrict__ w1, const float* __restrict__ w2,
    bf16* __restrict__ w1pp, bf16* __restrict__ w2pp)
{
    const int blk = blockIdx.x;
    const int t = threadIdx.x;
    if (blk < 2048) {
        int idx = blk * 256 + t;
        int h = idx >> 8, k = idx & 255;
        const float* wrow = w1 + (size_t)h * C_DIM;
        float acc = 0.f;
        int jlo = (k == 0) ? 0 : (int)((float)(k - 1) * (511.0f / 255.0f));
        int jhi = (int)((float)(k + 1) * (511.0f / 255.0f)) + 1;
        if (jhi > 511) jhi = 511;
        for (int j = jlo; j <= jhi; ++j) {
            float pos = (float)j * (255.0f / 511.0f);
            int i0 = (int)pos;
            if (i0 > 254) i0 = 254;
            float w = pos - (float)i0;
            float coef = (i0 == k) ? (1.0f - w) : ((i0 + 1 == k) ? w : 0.0f);
            acc += coef * wrow[j];
        }
        size_t frag = (size_t)(h >> 5) * 16 + (k >> 4);
        size_t lane = (size_t)(((k >> 3) & 1) << 5 | (h & 31));
        w1pp[frag * 512 + lane * 8 + (k & 7)] = (bf16)acc;
    } else {
        int idx2 = (blk - 2048) * 256 + t;     // 0..524287
        int c2 = idx2 >> 11, hid = idx2 & 2047;
        float v = w2[(size_t)c2 * HID + hid];
        size_t frag = (size_t)(c2 >> 5) * 128 + (hid >> 4);
        size_t lane = (size_t)(((hid >> 3) & 1) << 5 | (c2 & 31));
        w2pp[frag * 512 + lane * 8 + (hid & 7)] = (bf16)v;
    }
}

// ---------------- fused: DWT -> [G1 -> GELU -> G2] x 4 pairs -> iDWT ----------
// 512 blocks x 512 thr (8 waves), 32 rows/block, 2 blocks/CU (48KB LDS).
// ll held IN REGISTERS per wave (16 A-frags, read from LDS once).
// Pair = 512 hid. G1: wave = 32 rows x 64 hid (nf=2, pure-register inner loop).
// G2: wave = 32 rows x 32 c2 over pair's K=512. Zero weight duplication:
// block reads W1+W2 exactly once (2MB from L2).
__global__ __launch_bounds__(512, 2) void fused_mlp(
    const bf16* __restrict__ w1pp, const bf16* __restrict__ w2pp,
    const float* __restrict__ b1, const float* __restrict__ b2,
    const float* __restrict__ x, float* __restrict__ out)
{
    __shared__ __align__(16) char smem[49152];   // [0,16K) ll ; [16K,48K) Hs
    char* hsm = smem + 16384;

    const int tid = threadIdx.x;
    const int l   = tid & 63;
    const int wv  = tid >> 6;          // 0..7
    const int sub = wv >> 2;           // 0..1 : which 256-chunk of the pair
    const int sl4 = wv & 3;            // 0..3 : 64-hid slot within chunk
    const int R0  = blockIdx.x * 32;
    const char* w1B = (const char*)w1pp;
    const char* w2B = (const char*)w2pp;

    // ---- DWT: ll A-frag-packed into LDS. thread=(row r=tid&31, kf s=tid>>5);
    //      writes at s*1024 + ((jj<<5)|r)*16 -> consecutive lanes = consecutive
    //      16B slots (conflict-free). ----
    {
        const int r = tid & 31;
        const int s = tid >> 5;                // 0..15
        const int gbf = R0 + r;
        const float* xr0 = x + ((size_t)(gbf >> 7) * F_DIM + (size_t)(gbf & 127) * 2) * C_DIM;
        const float* xr1 = xr0 + C_DIM;
#pragma unroll
        for (int jj = 0; jj < 2; ++jj) {
            int j = s * 2 + jj;                // c2 in [8j, 8j+8)
            float4 a[4], b[4];
#pragma unroll
            for (int i = 0; i < 4; ++i) {
                a[i] = ((const float4*)xr0)[j * 4 + i];
                b[i] = ((const float4*)xr1)[j * 4 + i];
            }
            const float* pa = (const float*)a;
            const float* pb = (const float*)b;
            bf16x8 pk;
#pragma unroll
            for (int e = 0; e < 8; ++e)
                pk[e] = (bf16)(0.5f * (pa[2*e] + pa[2*e+1] + pb[2*e] + pb[2*e+1]));
            *(bf16x8*)(smem + s * 1024 + (size_t)((jj << 5) | r) * 16) = pk;
        }
    }
    __syncthreads();

    // ---- ll -> registers (once; reused for all 4 pairs) ----
    bf16x8 llr[16];
#pragma unroll
    for (int kf = 0; kf < 16; ++kf)
        llr[kf] = *(const bf16x8*)(smem + kf * 1024 + (size_t)l * 16);

    f32x16 acc2{};

#pragma unroll 1
    for (int pc = 0; pc < 4; ++pc) {
        // ===== GEMM1: acc1[nf] (32 rows x 64 hid), K=256, weights from L2 =====
        f32x16 acc1_0{}, acc1_1{};
        const int hb = pc * 16 + sub * 8 + sl4 * 2;       // 32-hid block row
        const char* w1f = w1B + ((size_t)hb * 16) * 1024 + (size_t)l * 16;
#pragma unroll
        for (int g = 0; g < 2; ++g) {
            bf16x8 wf0[8], wf1[8];
#pragma unroll
            for (int i = 0; i < 8; ++i) {
                wf0[i] = *(const bf16x8*)(w1f + (g * 8 + i) * 1024);
                wf1[i] = *(const bf16x8*)(w1f + (16 + g * 8 + i) * 1024);
            }
            SCHED0();
#pragma unroll
            for (int i = 0; i < 8; ++i) {
                acc1_0 = __builtin_amdgcn_mfma_f32_32x32x16_bf16(llr[g * 8 + i], wf0[i], acc1_0, 0, 0, 0);
                acc1_1 = __builtin_amdgcn_mfma_f32_32x32x16_bf16(llr[g * 8 + i], wf1[i], acc1_1, 0, 0, 0);
            }
        }

        // ===== GELU(+bias) -> Hs (A-frag-packed; DPP lane^1 pair pack) =====
#pragma unroll
        for (int nf = 0; nf < 2; ++nf) {
            const f32x16& A = nf ? acc1_1 : acc1_0;
            const int cin = sub * 256 + sl4 * 64 + nf * 32 + (l & 31);  // hid in pair
            const float bs = b1[pc * 512 + cin];
            const int kf2 = cin >> 4;
#pragma unroll
            for (int reg = 0; reg < 16; ++reg) {
                float v = A[reg] + bs;
                float tt = v * (0.79788456080f + 0.03567740814f * v * v);
                float g = v / (1.0f + __expf(-2.0f * tt));
                float gp = __builtin_bit_cast(float,
                    __builtin_amdgcn_mov_dpp(__builtin_bit_cast(int, g), 0xB1, 0xF, 0xF, true));
                if (!(l & 1)) {
                    unsigned u = (unsigned)bfbits(g) | ((unsigned)bfbits(gp) << 16);
                    int crow = (reg & 3) + 8 * (reg >> 2) + 4 * (l >> 5);
                    int lane2 = (((l >> 3) & 1) << 5) | crow;
                    *(unsigned*)(hsm + kf2 * 1024 + lane2 * 16 + (l & 7) * 2) = u;
                }
            }
        }
        __syncthreads();               // Hs(pair) complete

        // ===== GEMM2: acc2 += Hs x W2, K=512 (32 ksteps), wave = 32c2 =====
        const char* w2f = w2B + ((size_t)(wv * 128 + pc * 32)) * 1024 + (size_t)l * 16;
#pragma unroll
        for (int g = 0; g < 4; ++g) {
            bf16x8 wf[8];
#pragma unroll
            for (int i = 0; i < 8; ++i)
                wf[i] = *(const bf16x8*)(w2f + (g * 8 + i) * 1024);
            SCHED0();
#pragma unroll
            for (int i = 0; i < 8; ++i) {
                bf16x8 hfr = *(const bf16x8*)(hsm + (g * 8 + i) * 1024 + (size_t)l * 16);
                acc2 = __builtin_amdgcn_mfma_f32_32x32x16_bf16(hfr, wf[i], acc2, 0, 0, 0);
            }
        }
        __syncthreads();               // Hs consumed before next pair's GELU
    }

    // ---- epilogue: bias + iDWT  (out = x + 0.5*(ll_new - ll_old)) ----
    {
        const int c2 = wv * 32 + (l & 31);
        const float bs = b2[c2];
#pragma unroll
        for (int reg = 0; reg < 16; ++reg) {
            int R = R0 + (reg & 3) + 8 * (reg >> 2) + 4 * (l >> 5);
            int b = R >> 7, f2 = R & 127;
            const float* xr = x + ((size_t)b * F_DIM + (size_t)f2 * 2) * C_DIM;
            float2 p0 = ((const float2*)xr)[c2];
            float2 p1 = ((const float2*)(xr + C_DIM))[c2];
            float llo = 0.5f * (p0.x + p0.y + p1.x + p1.y);
            float d = 0.5f * ((acc2[reg] + bs) - llo);
            float2 o0, o1;
            o0.x = p0.x + d; o0.y = p0.y + d;
            o1.x = p1.x + d; o1.y = p1.y + d;
            float* orow = out + ((size_t)b * F_DIM + (size_t)f2 * 2) * C_DIM;
            ((float2*)orow)[c2] = o0;
            ((float2*)(orow + C_DIM))[c2] = o1;
        }
    }
}

extern "C" void kernel_launch(void* const* d_in, const int* in_sizes, int n_in,
                              void* d_out, int out_size, void* d_ws, size_t ws_size,
                              hipStream_t stream) {
    const float* x     = (const float*)d_in[0];
    const float* fc1_w = (const float*)d_in[1];
    const float* fc1_b = (const float*)d_in[2];
    const float* fc2_w = (const float*)d_in[3];
    const float* fc2_b = (const float*)d_in[4];
    float* out = (float*)d_out;

    char* ws = (char*)d_ws;
    bf16* w1pp = (bf16*)(ws + OFF_W1);
    bf16* w2pp = (bf16*)(ws + OFF_W2);

    prep_kernel<<<4096, 256, 0, stream>>>(fc1_w, fc2_w, w1pp, w2pp);
    fused_mlp<<<MROWS / 32, 512, 0, stream>>>(w1pp, w2pp, fc1_b, fc2_b, x, out);
}